// Round 6
// baseline (718.053 us; speedup 1.0000x reference)
//
#include <hip/hip_runtime.h>
#include <math.h>

#define T_ 1024
#define D_ 3
#define H_ 64

typedef _Float16 f16x8 __attribute__((ext_vector_type(8)));
typedef float f32x4 __attribute__((ext_vector_type(4)));

__device__ __forceinline__ float sigmoid_f(float x) {
    return __builtin_amdgcn_rcpf(1.0f + __expf(-x));
}

#define MFMA(A, B, C) __builtin_amdgcn_mfma_f32_16x16x32_f16((A), (B), (C), 0, 0, 0)

// 4 waves/block, 16 seqs/block, TWO independent GRU groups per wave:
//   group A = chain-1 (x1) rows = seqs [seq0,seq0+16), group B = chain-2 (x2).
// Wave w owns hidden units [16w,16w+16) for BOTH groups. The two groups'
// step bodies are interleaved -> two independent dep chains per wave (ILP
// replaces the TLP the 256-block grid can't provide). Shared overhead
// (weights, barrier, loop control) is NOT duplicated (round-4 lesson).
// exp2-folded weights (r,z rows * -log2e, n rows * 2log2e) -> bare v_exp;
// sigmoid pair shares one v_rcp. Siamese diff is a register subtract.
__global__ __launch_bounds__(256, 1) void gru_mfma6(
    const float* __restrict__ x1, const float* __restrict__ x2,
    const float* __restrict__ W_ih, const float* __restrict__ W_hh,
    const float* __restrict__ b_ih, const float* __restrict__ b_hh,
    const float* __restrict__ W1, const float* __restrict__ b1,
    const float* __restrict__ W2, const float* __restrict__ b2,
    float* __restrict__ out)
{
    const int lane = threadIdx.x & 63;
    const int w    = threadIdx.x >> 6;   // wave 0..3: owns units 16w..16w+15
    const int c    = lane & 15;          // A-m / C-D col / B-n
    const int q    = lane >> 4;          // quad
    const int u    = 16 * w + c;         // this lane's hidden-unit column
    const int seq0 = blockIdx.x * 16;

    const float SRZ = -1.44269504f;      // -log2(e): r,z rows (exp2(-x) form)
    const float SN  =  2.88539008f;      // 2*log2(e): n rows (exp2(2x) form)
    const float gsc[3] = {SRZ, SRZ, SN};

    // ---- h-part B-fragments (scaled): wf[g][ks][j] = s_g*W_hh[g*64+u][32ks+8q+j]
    f16x8 wf[3][2];
    #pragma unroll
    for (int g = 0; g < 3; ++g)
        #pragma unroll
        for (int ks = 0; ks < 2; ++ks) {
            const float* p = W_hh + (size_t)(g * 64 + u) * H_ + 32 * ks + q * 8;
            f16x8 v;
            #pragma unroll
            for (int j = 0; j < 8; ++j) v[j] = (_Float16)(p[j] * gsc[g]);
            wf[g][ks] = v;
        }

    // ---- x-part B-fragments (scaled; nonzero only in q==0 lanes, j<3) ----
    f16x8 bxf[3];
    #pragma unroll
    for (int g = 0; g < 3; ++g) {
        f16x8 v = {};
        if (q == 0) {
            #pragma unroll
            for (int d = 0; d < 3; ++d)
                v[d] = (_Float16)(W_ih[(size_t)(g * 64 + u) * D_ + d] * gsc[g]);
        }
        bxf[g] = v;
    }

    // ---- bias C-splats (scaled) ----
    const float comb_r = (b_ih[u]      + b_hh[u])      * SRZ;
    const float comb_z = (b_ih[64 + u] + b_hh[64 + u]) * SRZ;
    const float bxn    = b_ih[128 + u] * SN;
    const float bhn    = b_hh[128 + u] * SN;
    const f32x4 Cr  = {comb_r, comb_r, comb_r, comb_r};
    const f32x4 Cz  = {comb_z, comb_z, comb_z, comb_z};
    const f32x4 Cxn = {bxn, bxn, bxn, bxn};
    const f32x4 Chn = {bhn, bhn, bhn, bhn};

    // ---- x pointers: A-frag row c = seq seq0+c; group A = x1, B = x2 ----
    const float4* xpA = (const float4*)(x1 + (size_t)(seq0 + c) * (T_ * D_));
    const float4* xpB = (const float4*)(x2 + (size_t)(seq0 + c) * (T_ * D_));

    // h-tile double buffer per group: [row][unit], stride 72 halves
    __shared__ alignas(16) _Float16 hb[2][2][16 * 72];
    __shared__ float dlds[16][68];

    float hA[4], hB[4];                  // rows 4q+0..3, col u, per group
    #pragma unroll
    for (int r = 0; r < 4; ++r) { hA[r] = 0.f; hB[r] = 0.f; }

    auto step = [&](int buf, float a0x, float a1x, float a2x,
                             float b0x, float b1x, float b2x) {
        // publish both groups' h(t) first
        #pragma unroll
        for (int r = 0; r < 4; ++r) {
            hb[buf][0][(4 * q + r) * 72 + u] = (_Float16)hA[r];
            hb[buf][1][(4 * q + r) * 72 + u] = (_Float16)hB[r];
        }
        // x-part MFMAs for both groups: independent of h(t), pre-barrier
        f16x8 axA = {}, axB = {};
        axA[0] = (_Float16)a0x; axA[1] = (_Float16)a1x; axA[2] = (_Float16)a2x;
        axB[0] = (_Float16)b0x; axB[1] = (_Float16)b1x; axB[2] = (_Float16)b2x;
        f32x4 arA  = MFMA(axA, bxf[0], Cr);
        f32x4 arB  = MFMA(axB, bxf[0], Cr);
        f32x4 azA  = MFMA(axA, bxf[1], Cz);
        f32x4 azB  = MFMA(axB, bxf[1], Cz);
        f32x4 axnA = MFMA(axA, bxf[2], Cxn);
        f32x4 axnB = MFMA(axB, bxf[2], Cxn);
        __syncthreads();
        const f16x8 aA0 = *(const f16x8*)&hb[buf][0][c * 72 + q * 8];
        const f16x8 aA1 = *(const f16x8*)&hb[buf][0][c * 72 + 32 + q * 8];
        const f16x8 aB0 = *(const f16x8*)&hb[buf][1][c * 72 + q * 8];
        const f16x8 aB1 = *(const f16x8*)&hb[buf][1][c * 72 + 32 + q * 8];

        arA  = MFMA(aA0, wf[0][0], arA);
        arB  = MFMA(aB0, wf[0][0], arB);
        azA  = MFMA(aA0, wf[1][0], azA);
        azB  = MFMA(aB0, wf[1][0], azB);
        f32x4 ahnA = MFMA(aA0, wf[2][0], Chn);
        f32x4 ahnB = MFMA(aB0, wf[2][0], Chn);
        arA  = MFMA(aA1, wf[0][1], arA);
        arB  = MFMA(aB1, wf[0][1], arB);
        azA  = MFMA(aA1, wf[1][1], azA);
        azB  = MFMA(aB1, wf[1][1], azB);
        ahnA = MFMA(aA1, wf[2][1], ahnA);
        ahnB = MFMA(aB1, wf[2][1], ahnB);

        // gates: two independent chains interleaved
        #pragma unroll
        for (int r = 0; r < 4; ++r) {
            const float euA = __builtin_amdgcn_exp2f(arA[r]);
            const float euB = __builtin_amdgcn_exp2f(arB[r]);
            const float evA = __builtin_amdgcn_exp2f(azA[r]);
            const float evB = __builtin_amdgcn_exp2f(azB[r]);
            const float puA = 1.0f + euA, pvA = 1.0f + evA;
            const float puB = 1.0f + euB, pvB = 1.0f + evB;
            const float invA = __builtin_amdgcn_rcpf(puA * pvA);
            const float invB = __builtin_amdgcn_rcpf(puB * pvB);
            const float rrA = pvA * invA, zzA = puA * invA;
            const float rrB = pvB * invB, zzB = puB * invB;
            const float ttA = axnA[r] + rrA * ahnA[r];
            const float ttB = axnB[r] + rrB * ahnB[r];
            const float e2A = __builtin_amdgcn_exp2f(ttA);
            const float e2B = __builtin_amdgcn_exp2f(ttB);
            const float nnA = 1.0f - 2.0f * __builtin_amdgcn_rcpf(e2A + 1.0f);
            const float nnB = 1.0f - 2.0f * __builtin_amdgcn_rcpf(e2B + 1.0f);
            hA[r] = nnA + zzA * (hA[r] - nnA);
            hB[r] = nnB + zzB * (hB[r] - nnB);
        }
    };

    // x batching: 3 float4 per group per 4 steps, prefetch distance 4 steps
    float4 xcA[3], xcB[3];
    #pragma unroll
    for (int i = 0; i < 3; ++i) { xcA[i] = xpA[i]; xcB[i] = xpB[i]; }

    for (int t = 0; t < T_; t += 4) {
        float4 xnA[3], xnB[3];
        const int tb = (t + 4 < T_) ? (3 * (t + 4)) / 4 : (3 * t) / 4;
        #pragma unroll
        for (int i = 0; i < 3; ++i) { xnA[i] = xpA[tb + i]; xnB[i] = xpB[tb + i]; }
        step(0, xcA[0].x, xcA[0].y, xcA[0].z, xcB[0].x, xcB[0].y, xcB[0].z);
        step(1, xcA[0].w, xcA[1].x, xcA[1].y, xcB[0].w, xcB[1].x, xcB[1].y);
        step(0, xcA[1].z, xcA[1].w, xcA[2].x, xcB[1].z, xcB[1].w, xcB[2].x);
        step(1, xcA[2].y, xcA[2].z, xcA[2].w, xcB[2].y, xcB[2].z, xcB[2].w);
        #pragma unroll
        for (int i = 0; i < 3; ++i) { xcA[i] = xnA[i]; xcB[i] = xnB[i]; }
    }

    // ---- epilogue: |hA-hB| (register diff) -> MLP for 16 seqs ----
    #pragma unroll
    for (int r = 0; r < 4; ++r)
        dlds[4 * q + r][u] = fabsf(hA[r] - hB[r]);
    __syncthreads();
    if (w < 2) {
        const int s = 8 * w + (lane >> 3);   // seq within block 0..15
        const int b = lane & 7;              // hidden-row group base
        float am[4];
        #pragma unroll
        for (int i = 0; i < 4; ++i) am[i] = b1[b + 8 * i];
        #pragma unroll
        for (int k4 = 0; k4 < 16; ++k4) {
            const float4 dvec = *(const float4*)&dlds[s][k4 * 4];
            #pragma unroll
            for (int i = 0; i < 4; ++i) {
                const float4 wv = *(const float4*)&W1[(b + 8 * i) * H_ + k4 * 4];
                am[i] += dvec.x * wv.x + dvec.y * wv.y + dvec.z * wv.z + dvec.w * wv.w;
            }
        }
        float part = 0.f;
        #pragma unroll
        for (int i = 0; i < 4; ++i) part += fmaxf(am[i], 0.f) * W2[b + 8 * i];
        part += __shfl_xor(part, 1);
        part += __shfl_xor(part, 2);
        part += __shfl_xor(part, 4);
        if (b == 0) out[seq0 + s] = sigmoid_f(part + b2[0]);
    }
}

extern "C" void kernel_launch(void* const* d_in, const int* in_sizes, int n_in,
                              void* d_out, int out_size, void* d_ws, size_t ws_size,
                              hipStream_t stream) {
    const float* x1   = (const float*)d_in[0];
    const float* x2   = (const float*)d_in[1];
    const float* W_ih = (const float*)d_in[2];
    const float* W_hh = (const float*)d_in[3];
    const float* b_ih = (const float*)d_in[4];
    const float* b_hh = (const float*)d_in[5];
    const float* W1   = (const float*)d_in[6];
    const float* b1   = (const float*)d_in[7];
    const float* W2   = (const float*)d_in[8];
    const float* b2   = (const float*)d_in[9];

    const int B = in_sizes[0] / (T_ * D_);      // 4096
    dim3 grid(B / 16), block(256);
    gru_mfma6<<<grid, block, 0, stream>>>(x1, x2, W_ih, W_hh, b_ih, b_hh,
                                          W1, b1, W2, b2, (float*)d_out);
}

// Round 7
// 637.637 us; speedup vs baseline: 1.1261x; 1.1261x over previous
//
#include <hip/hip_runtime.h>
#include <math.h>

#define T_ 1024
#define D_ 3
#define H_ 64

typedef _Float16 f16x8 __attribute__((ext_vector_type(8)));
typedef float f32x4 __attribute__((ext_vector_type(4)));

__device__ __forceinline__ float sigmoid_f(float x) {
    return __builtin_amdgcn_rcpf(1.0f + __expf(-x));
}

#define MFMA(A, B, C) __builtin_amdgcn_mfma_f32_16x16x32_f16((A), (B), (C), 0, 0, 0)

// Round-5 structure (best: 578 us) + critical-path trims.
// 4 waves/block, one 16-row tile (8 seqs x 2 chains); wave w owns units
// [16w,16w+16). Per step: publish h -> x-MFMAs (pre-barrier) -> barrier ->
// ar/az MFMAs first (rr needs both via shared rcp), ahn last with split-C
// (a1-half accumulates into zero C, summed by v_add -> no serial MFMA dep).
// exp2-folded weights; 8-step unroll.
__global__ __launch_bounds__(256, 2) void gru_mfma7(
    const float* __restrict__ x1, const float* __restrict__ x2,
    const float* __restrict__ W_ih, const float* __restrict__ W_hh,
    const float* __restrict__ b_ih, const float* __restrict__ b_hh,
    const float* __restrict__ W1, const float* __restrict__ b1,
    const float* __restrict__ W2, const float* __restrict__ b2,
    float* __restrict__ out)
{
    const int lane = threadIdx.x & 63;
    const int w    = threadIdx.x >> 6;   // wave 0..3: owns units 16w..16w+15
    const int c    = lane & 15;          // A-m / C-D col / B-n
    const int q    = lane >> 4;          // quad
    const int u    = 16 * w + c;         // this lane's hidden-unit column
    const int seq0 = blockIdx.x * 8;

    const float SRZ = -1.44269504f;      // -log2(e): r,z rows (exp2(-x) form)
    const float SN  =  2.88539008f;      // 2*log2(e): n rows (exp2(2x) form)
    const float gsc[3] = {SRZ, SRZ, SN};

    // ---- h-part B-fragments (scaled): wf[g][ks][j] = s_g*W_hh[g*64+u][32ks+8q+j]
    f16x8 wf[3][2];
    #pragma unroll
    for (int g = 0; g < 3; ++g)
        #pragma unroll
        for (int ks = 0; ks < 2; ++ks) {
            const float* p = W_hh + (size_t)(g * 64 + u) * H_ + 32 * ks + q * 8;
            f16x8 v;
            #pragma unroll
            for (int j = 0; j < 8; ++j) v[j] = (_Float16)(p[j] * gsc[g]);
            wf[g][ks] = v;
        }

    // ---- x-part B-fragments (scaled; nonzero only in q==0 lanes, j<3) ----
    f16x8 bxf[3];
    #pragma unroll
    for (int g = 0; g < 3; ++g) {
        f16x8 v = {};
        if (q == 0) {
            #pragma unroll
            for (int d = 0; d < 3; ++d)
                v[d] = (_Float16)(W_ih[(size_t)(g * 64 + u) * D_ + d] * gsc[g]);
        }
        bxf[g] = v;
    }

    // ---- bias C-splats (scaled) ----
    const float comb_r = (b_ih[u]      + b_hh[u])      * SRZ;
    const float comb_z = (b_ih[64 + u] + b_hh[64 + u]) * SRZ;
    const float bxn    = b_ih[128 + u] * SN;
    const float bhn    = b_hh[128 + u] * SN;
    const f32x4 Cr  = {comb_r, comb_r, comb_r, comb_r};
    const f32x4 Cz  = {comb_z, comb_z, comb_z, comb_z};
    const f32x4 Cxn = {bxn, bxn, bxn, bxn};
    const f32x4 Chn = {bhn, bhn, bhn, bhn};
    const f32x4 Z4  = {0.f, 0.f, 0.f, 0.f};

    // ---- x pointer for A-frag row c (rows 0..7 = chain1, 8..15 = chain2) ----
    const float* xptr = (c < 8) ? (x1 + (size_t)(seq0 + c) * (T_ * D_))
                                : (x2 + (size_t)(seq0 + c - 8) * (T_ * D_));

    // h-tile double buffer: [row][unit], stride 72 halves
    __shared__ alignas(16) _Float16 hb[2][16 * 72];
    __shared__ float dlds[8][68];

    float h[4];                          // rows 4q+0..3, col u
    #pragma unroll
    for (int r = 0; r < 4; ++r) h[r] = 0.f;

    auto step = [&](int buf, float x0, float x1v, float x2v) {
        // publish h(t) first — other waves' barrier wait ends sooner
        #pragma unroll
        for (int r = 0; r < 4; ++r)
            hb[buf][(4 * q + r) * 72 + u] = (_Float16)h[r];
        // x-part MFMAs: independent of h(t), fill the pre-barrier gap
        f16x8 ax = {};
        ax[0] = (_Float16)x0; ax[1] = (_Float16)x1v; ax[2] = (_Float16)x2v;
        f32x4 ar  = MFMA(ax, bxf[0], Cr);
        f32x4 az  = MFMA(ax, bxf[1], Cz);
        f32x4 axn = MFMA(ax, bxf[2], Cxn);
        __syncthreads();
        const f16x8 a0 = *(const f16x8*)&hb[buf][c * 72 + q * 8];        // k 0..31
        const f16x8 a1 = *(const f16x8*)&hb[buf][c * 72 + 32 + q * 8];   // k 32..63

        // ar/az first (rr needs both through the shared rcp); ahn split-C:
        // the a1 half accumulates into zero C concurrently, summed by v_add.
        ar = MFMA(a0, wf[0][0], ar);
        az = MFMA(a0, wf[1][0], az);
        ar = MFMA(a1, wf[0][1], ar);
        az = MFMA(a1, wf[1][1], az);
        f32x4 ahn0 = MFMA(a0, wf[2][0], Chn);
        f32x4 ahn1 = MFMA(a1, wf[2][1], Z4);

        // gates: ar,az hold -log2e*preact; axn,ahn hold 2log2e*parts
        #pragma unroll
        for (int r = 0; r < 4; ++r) {
            const float eu = __builtin_amdgcn_exp2f(ar[r]);   // e^{-pre_r}
            const float ev = __builtin_amdgcn_exp2f(az[r]);   // e^{-pre_z}
            const float pu = 1.0f + eu, pv = 1.0f + ev;
            const float inv = __builtin_amdgcn_rcpf(pu * pv);
            const float rr = pv * inv;                        // sigmoid(pre_r)
            const float zz = pu * inv;                        // sigmoid(pre_z)
            const float ahn = ahn0[r] + ahn1[r];
            const float tt = axn[r] + rr * ahn;               // 2log2e * pre_n
            const float e2 = __builtin_amdgcn_exp2f(tt);      // e^{2 pre_n}
            const float nn = 1.0f - 2.0f * __builtin_amdgcn_rcpf(e2 + 1.0f);
            h[r] = nn + zz * (h[r] - nn);
        }
    };

    // x batched: 6 x float4 = 18 floats = 8 steps per iter; prefetch 8 ahead
    const float4* xp4 = (const float4*)xptr;
    float4 xc[6];
    #pragma unroll
    for (int i = 0; i < 6; ++i) xc[i] = xp4[i];

    for (int t = 0; t < T_; t += 8) {
        float4 xn[6];
        const int tb = (t + 8 < T_) ? (3 * (t + 8)) / 4 : (3 * t) / 4;
        #pragma unroll
        for (int i = 0; i < 6; ++i) xn[i] = xp4[tb + i];
        step(0, xc[0].x, xc[0].y, xc[0].z);
        step(1, xc[0].w, xc[1].x, xc[1].y);
        step(0, xc[1].z, xc[1].w, xc[2].x);
        step(1, xc[2].y, xc[2].z, xc[2].w);
        step(0, xc[3].x, xc[3].y, xc[3].z);
        step(1, xc[3].w, xc[4].x, xc[4].y);
        step(0, xc[4].z, xc[4].w, xc[5].x);
        step(1, xc[5].y, xc[5].z, xc[5].w);
        #pragma unroll
        for (int i = 0; i < 6; ++i) xc[i] = xn[i];
    }

    // ---- epilogue: |h1-h2| -> Linear(64,32)+ReLU -> Linear(32,1)+sigmoid ----
    #pragma unroll
    for (int r = 0; r < 4; ++r) {
        const float o = __shfl_xor(h[r], 32);     // row m <-> m^8 (q ^= 2)
        if (q < 2) dlds[4 * q + r][u] = fabsf(h[r] - o);
    }
    __syncthreads();
    if (w == 0) {
        const int s = lane >> 3;   // seq within block 0..7
        const int b = lane & 7;    // hidden-row group base
        float am[4];
        #pragma unroll
        for (int i = 0; i < 4; ++i) am[i] = b1[b + 8 * i];
        #pragma unroll
        for (int k4 = 0; k4 < 16; ++k4) {
            const float4 dvec = *(const float4*)&dlds[s][k4 * 4];
            #pragma unroll
            for (int i = 0; i < 4; ++i) {
                const float4 wv = *(const float4*)&W1[(b + 8 * i) * H_ + k4 * 4];
                am[i] += dvec.x * wv.x + dvec.y * wv.y + dvec.z * wv.z + dvec.w * wv.w;
            }
        }
        float part = 0.f;
        #pragma unroll
        for (int i = 0; i < 4; ++i) part += fmaxf(am[i], 0.f) * W2[b + 8 * i];
        part += __shfl_xor(part, 1);
        part += __shfl_xor(part, 2);
        part += __shfl_xor(part, 4);
        if (b == 0) out[seq0 + s] = sigmoid_f(part + b2[0]);
    }
}

extern "C" void kernel_launch(void* const* d_in, const int* in_sizes, int n_in,
                              void* d_out, int out_size, void* d_ws, size_t ws_size,
                              hipStream_t stream) {
    const float* x1   = (const float*)d_in[0];
    const float* x2   = (const float*)d_in[1];
    const float* W_ih = (const float*)d_in[2];
    const float* W_hh = (const float*)d_in[3];
    const float* b_ih = (const float*)d_in[4];
    const float* b_hh = (const float*)d_in[5];
    const float* W1   = (const float*)d_in[6];
    const float* b1   = (const float*)d_in[7];
    const float* W2   = (const float*)d_in[8];
    const float* b2   = (const float*)d_in[9];

    const int B = in_sizes[0] / (T_ * D_);      // 4096
    dim3 grid(B / 8), block(256);
    gru_mfma7<<<grid, block, 0, stream>>>(x1, x2, W_ih, W_hh, b_ih, b_hh,
                                          W1, b1, W2, b2, (float*)d_out);
}

// Round 8
// 584.849 us; speedup vs baseline: 1.2278x; 1.0903x over previous
//
#include <hip/hip_runtime.h>
#include <math.h>

#define T_ 1024
#define D_ 3
#define H_ 64

typedef _Float16 f16x8 __attribute__((ext_vector_type(8)));
typedef float f32x4 __attribute__((ext_vector_type(4)));

__device__ __forceinline__ float sigmoid_f(float x) {
    return __builtin_amdgcn_rcpf(1.0f + __expf(-x));
}

#define MFMA(A, B, C) __builtin_amdgcn_mfma_f32_16x16x32_f16((A), (B), (C), 0, 0, 0)

// LDS-only barrier: cross-wave correctness at the step barrier needs only the
// ds_writes visible (lgkmcnt). __syncthreads() would also drain vmcnt(0),
// forcibly completing the x-prefetch global loads at every barrier — this
// variant lets them stay in flight across steps (true prefetch).
#define LDS_BARRIER() asm volatile("s_waitcnt lgkmcnt(0)\ns_barrier" ::: "memory")

// Round-5 structure (best: 578 us) + lgkm-only step barrier + MFMA reorder.
// 4 waves/block, one 16-row tile (8 seqs x 2 Siamese chains); wave w owns
// units [16w,16w+16). Per step: publish h -> x-MFMAs (pre-barrier) -> barrier
// -> ar/az MFMAs first (rr needs both via shared rcp), ahn after -> gates.
// exp2-folded weights (r,z rows * -log2e, n rows * 2log2e) -> bare v_exp;
// sigmoid pair shares one v_rcp.
__global__ __launch_bounds__(256, 2) void gru_mfma9(
    const float* __restrict__ x1, const float* __restrict__ x2,
    const float* __restrict__ W_ih, const float* __restrict__ W_hh,
    const float* __restrict__ b_ih, const float* __restrict__ b_hh,
    const float* __restrict__ W1, const float* __restrict__ b1,
    const float* __restrict__ W2, const float* __restrict__ b2,
    float* __restrict__ out)
{
    const int lane = threadIdx.x & 63;
    const int w    = threadIdx.x >> 6;   // wave 0..3: owns units 16w..16w+15
    const int c    = lane & 15;          // A-m / C-D col / B-n
    const int q    = lane >> 4;          // quad
    const int u    = 16 * w + c;         // this lane's hidden-unit column
    const int seq0 = blockIdx.x * 8;

    const float SRZ = -1.44269504f;      // -log2(e): r,z rows (exp2(-x) form)
    const float SN  =  2.88539008f;      // 2*log2(e): n rows (exp2(2x) form)
    const float gsc[3] = {SRZ, SRZ, SN};

    // ---- h-part B-fragments (scaled): wf[g][ks][j] = s_g*W_hh[g*64+u][32ks+8q+j]
    f16x8 wf[3][2];
    #pragma unroll
    for (int g = 0; g < 3; ++g)
        #pragma unroll
        for (int ks = 0; ks < 2; ++ks) {
            const float* p = W_hh + (size_t)(g * 64 + u) * H_ + 32 * ks + q * 8;
            f16x8 v;
            #pragma unroll
            for (int j = 0; j < 8; ++j) v[j] = (_Float16)(p[j] * gsc[g]);
            wf[g][ks] = v;
        }

    // ---- x-part B-fragments (scaled; nonzero only in q==0 lanes, j<3) ----
    f16x8 bxf[3];
    #pragma unroll
    for (int g = 0; g < 3; ++g) {
        f16x8 v = {};
        if (q == 0) {
            #pragma unroll
            for (int d = 0; d < 3; ++d)
                v[d] = (_Float16)(W_ih[(size_t)(g * 64 + u) * D_ + d] * gsc[g]);
        }
        bxf[g] = v;
    }

    // ---- bias C-splats (scaled) ----
    const float comb_r = (b_ih[u]      + b_hh[u])      * SRZ;
    const float comb_z = (b_ih[64 + u] + b_hh[64 + u]) * SRZ;
    const float bxn    = b_ih[128 + u] * SN;
    const float bhn    = b_hh[128 + u] * SN;
    const f32x4 Cr  = {comb_r, comb_r, comb_r, comb_r};
    const f32x4 Cz  = {comb_z, comb_z, comb_z, comb_z};
    const f32x4 Cxn = {bxn, bxn, bxn, bxn};
    const f32x4 Chn = {bhn, bhn, bhn, bhn};

    // ---- x pointer for A-frag row c (rows 0..7 = chain1, 8..15 = chain2) ----
    const float* xptr = (c < 8) ? (x1 + (size_t)(seq0 + c) * (T_ * D_))
                                : (x2 + (size_t)(seq0 + c - 8) * (T_ * D_));

    // h-tile double buffer: [row][unit], stride 72 halves
    __shared__ alignas(16) _Float16 hb[2][16 * 72];
    __shared__ float dlds[8][68];

    float h[4];                          // rows 4q+0..3, col u
    #pragma unroll
    for (int r = 0; r < 4; ++r) h[r] = 0.f;

    auto step = [&](int buf, float x0, float x1v, float x2v) {
        // publish h(t) first — other waves' barrier wait ends sooner
        #pragma unroll
        for (int r = 0; r < 4; ++r)
            hb[buf][(4 * q + r) * 72 + u] = (_Float16)h[r];
        // x-part MFMAs: independent of h(t), fill the pre-barrier gap.
        // No lane masking needed: bxf is zero wherever ax is junk.
        f16x8 ax = {};
        ax[0] = (_Float16)x0; ax[1] = (_Float16)x1v; ax[2] = (_Float16)x2v;
        f32x4 ar  = MFMA(ax, bxf[0], Cr);
        f32x4 az  = MFMA(ax, bxf[1], Cz);
        f32x4 axn = MFMA(ax, bxf[2], Cxn);
        LDS_BARRIER();                   // lgkm-only: x loads stay in flight
        const f16x8 a0 = *(const f16x8*)&hb[buf][c * 72 + q * 8];        // k 0..31
        const f16x8 a1 = *(const f16x8*)&hb[buf][c * 72 + 32 + q * 8];   // k 32..63

        // ar/az first: rr needs both (shared rcp) before tt needs ahn
        ar = MFMA(a0, wf[0][0], ar);
        az = MFMA(a0, wf[1][0], az);
        ar = MFMA(a1, wf[0][1], ar);
        az = MFMA(a1, wf[1][1], az);
        f32x4 ahn = MFMA(a0, wf[2][0], Chn);
        ahn = MFMA(a1, wf[2][1], ahn);

        // gates: ar,az hold -log2e*preact; axn,ahn hold 2log2e*parts
        #pragma unroll
        for (int r = 0; r < 4; ++r) {
            const float eu = __builtin_amdgcn_exp2f(ar[r]);   // e^{-pre_r}
            const float ev = __builtin_amdgcn_exp2f(az[r]);   // e^{-pre_z}
            const float pu = 1.0f + eu, pv = 1.0f + ev;
            const float inv = __builtin_amdgcn_rcpf(pu * pv);
            const float rr = pv * inv;                        // sigmoid(pre_r)
            const float zz = pu * inv;                        // sigmoid(pre_z)
            const float tt = axn[r] + rr * ahn[r];            // 2log2e * pre_n
            const float e2 = __builtin_amdgcn_exp2f(tt);      // e^{2 pre_n}
            const float nn = 1.0f - 2.0f * __builtin_amdgcn_rcpf(e2 + 1.0f);
            h[r] = nn + zz * (h[r] - nn);
        }
    };

    // x batched: float4 x3 = 12 floats = 4 steps; prefetch distance 4 steps
    const float4* xp4 = (const float4*)xptr;
    float4 xc[3];
    #pragma unroll
    for (int i = 0; i < 3; ++i) xc[i] = xp4[i];

    for (int t = 0; t < T_; t += 4) {
        float4 xn[3];
        const int tb = (t + 4 < T_) ? (3 * (t + 4)) / 4 : (3 * t) / 4;
        #pragma unroll
        for (int i = 0; i < 3; ++i) xn[i] = xp4[tb + i];
        step(0, xc[0].x, xc[0].y, xc[0].z);
        step(1, xc[0].w, xc[1].x, xc[1].y);
        step(0, xc[1].z, xc[1].w, xc[2].x);
        step(1, xc[2].y, xc[2].z, xc[2].w);
        #pragma unroll
        for (int i = 0; i < 3; ++i) xc[i] = xn[i];
    }

    // ---- epilogue: |h1-h2| -> Linear(64,32)+ReLU -> Linear(32,1)+sigmoid ----
    #pragma unroll
    for (int r = 0; r < 4; ++r) {
        const float o = __shfl_xor(h[r], 32);     // row m <-> m^8 (q ^= 2)
        if (q < 2) dlds[4 * q + r][u] = fabsf(h[r] - o);
    }
    __syncthreads();
    if (w == 0) {
        const int s = lane >> 3;   // seq within block 0..7
        const int b = lane & 7;    // hidden-row group base
        float am[4];
        #pragma unroll
        for (int i = 0; i < 4; ++i) am[i] = b1[b + 8 * i];
        #pragma unroll
        for (int k4 = 0; k4 < 16; ++k4) {
            const float4 dvec = *(const float4*)&dlds[s][k4 * 4];
            #pragma unroll
            for (int i = 0; i < 4; ++i) {
                const float4 wv = *(const float4*)&W1[(b + 8 * i) * H_ + k4 * 4];
                am[i] += dvec.x * wv.x + dvec.y * wv.y + dvec.z * wv.z + dvec.w * wv.w;
            }
        }
        float part = 0.f;
        #pragma unroll
        for (int i = 0; i < 4; ++i) part += fmaxf(am[i], 0.f) * W2[b + 8 * i];
        part += __shfl_xor(part, 1);
        part += __shfl_xor(part, 2);
        part += __shfl_xor(part, 4);
        if (b == 0) out[seq0 + s] = sigmoid_f(part + b2[0]);
    }
}

extern "C" void kernel_launch(void* const* d_in, const int* in_sizes, int n_in,
                              void* d_out, int out_size, void* d_ws, size_t ws_size,
                              hipStream_t stream) {
    const float* x1   = (const float*)d_in[0];
    const float* x2   = (const float*)d_in[1];
    const float* W_ih = (const float*)d_in[2];
    const float* W_hh = (const float*)d_in[3];
    const float* b_ih = (const float*)d_in[4];
    const float* b_hh = (const float*)d_in[5];
    const float* W1   = (const float*)d_in[6];
    const float* b1   = (const float*)d_in[7];
    const float* W2   = (const float*)d_in[8];
    const float* b2   = (const float*)d_in[9];

    const int B = in_sizes[0] / (T_ * D_);      // 4096
    dim3 grid(B / 8), block(256);
    gru_mfma9<<<grid, block, 0, stream>>>(x1, x2, W_ih, W_hh, b_ih, b_hh,
                                          W1, b1, W2, b2, (float*)d_out);
}